// Round 6
// baseline (202.007 us; speedup 1.0000x reference)
//
#include <hip/hip_runtime.h>
#include <hip/hip_fp16.h>
#include <stdint.h>
#include <math.h>

#define KB 512
#define KT 2048
#define KS 16
#define KPD 4
#define TILE 128
#define NTILE (KT / TILE)

typedef uint32_t u32x2 __attribute__((ext_vector_type(2)));
typedef float    f32x2 __attribute__((ext_vector_type(2)));
typedef float    f32x4 __attribute__((ext_vector_type(4)));

// ---------------- shared helpers ----------------
__device__ __forceinline__ float softplus_f(float x) {
    float ax = fabsf(x);
    float e  = __expf(-ax);
    return fmaxf(x, 0.0f) + __logf(1.0f + e);
}
__device__ __forceinline__ float sigmoid_f(float x) {
    return __builtin_amdgcn_rcpf(1.0f + __expf(-x));
}

__device__ __forceinline__ void mlp16(const float4 pv,
    const float* __restrict__ W1, const float* __restrict__ b1,
    const float* __restrict__ W2, const float* __restrict__ b2,
    float* __restrict__ acc)
{
#pragma unroll
    for (int j = 0; j < KS; ++j) acc[j] = b2[j];
#pragma unroll 4
    for (int k = 0; k < 64; ++k) {
        float hk = b1[k];
        hk = fmaf(pv.x, W1[k],       hk);
        hk = fmaf(pv.y, W1[64 + k],  hk);
        hk = fmaf(pv.z, W1[128 + k], hk);
        hk = fmaf(pv.w, W1[192 + k], hk);
        hk = fmaxf(hk, 0.0f);
#pragma unroll
        for (int j = 0; j < KS; ++j) acc[j] = fmaf(hk, W2[k * KS + j], acc[j]);
    }
}

// ---------------- K1: embarrassingly-parallel MLPs (unchanged from R5) ----------------
// ws layout: qr_ws[b][t][s] (u32 = fp16 Q | fp16 R << 16), g_ws[b][t] (f32)
__global__ __launch_bounds__(256) void mlp_kernel(
    const float* __restrict__ p,
    const float* __restrict__ Wq1, const float* __restrict__ bq1,
    const float* __restrict__ Wq2, const float* __restrict__ bq2,
    const float* __restrict__ Wr1, const float* __restrict__ br1,
    const float* __restrict__ Wr2, const float* __restrict__ br2,
    const float* __restrict__ Wg1, const float* __restrict__ bg1,
    const float* __restrict__ Wg2, const float* __restrict__ bg2,
    uint32_t* __restrict__ qr_ws, float* __restrict__ g_ws)
{
    const int idx = blockIdx.x * 256 + threadIdx.x;   // global (b,t)
    const float4 pv = reinterpret_cast<const float4*>(p)[idx];

    float accQ[KS], accR[KS];
    mlp16(pv, Wq1, bq1, Wq2, bq2, accQ);
    mlp16(pv, Wr1, br1, Wr2, br2, accR);

    float ag = bg2[0];
#pragma unroll 4
    for (int k = 0; k < 32; ++k) {
        float hk = bg1[k];
        hk = fmaf(pv.x, Wg1[k],      hk);
        hk = fmaf(pv.y, Wg1[32 + k], hk);
        hk = fmaf(pv.z, Wg1[64 + k], hk);
        hk = fmaf(pv.w, Wg1[96 + k], hk);
        hk = fmaxf(hk, 0.0f);
        ag = fmaf(hk, Wg2[k], ag);
    }
    g_ws[idx] = sigmoid_f(ag);

    uint32_t wv[KS];
#pragma unroll
    for (int j = 0; j < KS; ++j) {
        float Qv = softplus_f(accQ[j]) + 1e-8f;
        float Rv = softplus_f(accR[j]) + 1e-8f;
        uint32_t lo = (uint32_t)__half_as_ushort(__float2half_rn(Qv));
        uint32_t hi = (uint32_t)__half_as_ushort(__float2half_rn(Rv));
        wv[j] = lo | (hi << 16);
    }
    uint4* qb = reinterpret_cast<uint4*>(qr_ws + ((size_t)idx << 4));
#pragma unroll
    for (int i = 0; i < 4; ++i)
        qb[i] = make_uint4(wv[4*i], wv[4*i+1], wv[4*i+2], wv[4*i+3]);
}

// ---------------- K2: LDS-staged scan, asm-pinned pipeline ----------------
__device__ __forceinline__ float h2f_lo(uint32_t w) {
    return __half2float(__ushort_as_half((unsigned short)(w & 0xffffu)));
}
__device__ __forceinline__ float h2f_hi(uint32_t w) {
    return __half2float(__ushort_as_half((unsigned short)(w >> 16)));
}

__device__ __forceinline__ uint32_t lds_off(const void* p) {
    // AS3 pointers are 32-bit LDS byte offsets
    return (uint32_t)(uintptr_t)(const __attribute__((address_space(3))) char*)p;
}

// ds_read2_b32: two 4-B reads at addr+0 and addr+64B (16 dwords apart = next t, same s)
#define DSR2U(d, a) asm volatile("ds_read2_b32 %0, %1 offset0:0 offset1:16" : "=v"(d) : "v"(a))
#define DSR2F(d, a) asm volatile("ds_read2_b32 %0, %1 offset0:0 offset1:16" : "=v"(d) : "v"(a))
#define DSR128(d, a) asm volatile("ds_read_b128 %0, %1" : "=v"(d) : "v"(a))
#define LGKM_WAIT(n) do { \
    asm volatile("s_waitcnt lgkmcnt(" #n ")" ::: "memory"); \
    __builtin_amdgcn_sched_barrier(0); } while (0)

struct Grp4 {           // 4 time-steps of data, 12 VGPRs
    u32x2 qr[2];
    f32x2 zz[2];
    f32x4 gg;
};

// issue exactly 5 LDS ops for group j (t0 = 4j)
__device__ __forceinline__ void issue_grp(Grp4& G, uint32_t qrb, uint32_t zbb,
                                          uint32_t gbb, int j)
{
    const uint32_t o = (uint32_t)(256 * j);     // 4j * 64 B row stride
    DSR2U(G.qr[0], qrb + o);
    DSR2U(G.qr[1], qrb + o + 128u);
    DSR2F(G.zz[0], zbb + o);
    DSR2F(G.zz[1], zbb + o + 128u);
    DSR128(G.gg, gbb + (uint32_t)(16 * j));
}

__device__ __forceinline__ void kstep(float& mu, float& Pv, float Q, float R,
                                      float zv, float gv)
{
    float Pp = Pv + Q;
    float K0 = Pp * __builtin_amdgcn_rcpf(Pp + R);
    float Kk = __builtin_amdgcn_fmed3f(K0, 1e-6f, 0.95f);
    mu = fmaf(gv * Kk, zv - mu, mu);
    Pv = fmaf(-Kk, Pp, Pp);
}

__device__ __forceinline__ void consume_grp(const Grp4& G, float& mu, float& Pv,
                                            float* __restrict__ op)
{
#pragma unroll
    for (int q = 0; q < 2; ++q) {
        float Q0 = h2f_lo(G.qr[q].x), R0 = h2f_hi(G.qr[q].x);
        float Q1 = h2f_lo(G.qr[q].y), R1 = h2f_hi(G.qr[q].y);
        kstep(mu, Pv, Q0, R0, G.zz[q].x, G.gg[2 * q]);
        op[(2 * q) * KS] = mu;
        kstep(mu, Pv, Q1, R1, G.zz[q].y, G.gg[2 * q + 1]);
        op[(2 * q + 1) * KS] = mu;
    }
}

__global__ __launch_bounds__(64) void scan_kernel(
    const uint32_t* __restrict__ qr_ws, const float* __restrict__ g_ws,
    const float* __restrict__ z, const float* __restrict__ mu0,
    const float* __restrict__ P0, float* __restrict__ out)
{
    __shared__ uint32_t sQR[2][TILE][KS];   // 16 KB, [t][s]
    __shared__ float    sZ [2][TILE][KS];   // 16 KB, [t][s]
    __shared__ float    sG [2][TILE];       //  1 KB

    const int b = blockIdx.x;
    const int lane = threadIdx.x;           // 0..63
    const uint32_t* qb = qr_ws + (size_t)b * KT * KS;
    const float* zb = z + (size_t)b * KT * KS;
    const float* gb = g_ws + (size_t)b * KT;
    float* ob = out + (size_t)b * KT * KS;

    auto stage = [&](int tile, int buf) {
        const char* zsrc = (const char*)(zb + (size_t)tile * TILE * KS) + lane * 16;
        const char* qsrc = (const char*)(qb + (size_t)tile * TILE * KS) + lane * 16;
#pragma unroll
        for (int i = 0; i < 8; ++i) {
            __builtin_amdgcn_global_load_lds(
                (const __attribute__((address_space(1))) uint32_t*)(zsrc + i * 1024),
                (__attribute__((address_space(3))) uint32_t*)&sZ[buf][i * 16][0],
                16, 0, 0);
            __builtin_amdgcn_global_load_lds(
                (const __attribute__((address_space(1))) uint32_t*)(qsrc + i * 1024),
                (__attribute__((address_space(3))) uint32_t*)&sQR[buf][i * 16][0],
                16, 0, 0);
        }
        const char* gsrc = (const char*)(gb + (size_t)tile * TILE) + lane * 4;
#pragma unroll
        for (int i = 0; i < 2; ++i) {
            __builtin_amdgcn_global_load_lds(
                (const __attribute__((address_space(1))) uint32_t*)(gsrc + i * 256),
                (__attribute__((address_space(3))) uint32_t*)&sG[buf][i * 64],
                4, 0, 0);
        }
    };

    float mu = 0.0f, Pv = 0.0f;
    if (lane < KS) {
        mu = mu0[b * KS + lane];
        Pv = P0[b * KS + lane];
    }

    stage(0, 0);
    asm volatile("s_waitcnt vmcnt(0)" ::: "memory");
    __builtin_amdgcn_sched_barrier(0);

    for (int k = 0; k < NTILE; ++k) {
        const int buf = k & 1;
        if (k + 1 < NTILE) stage(k + 1, buf ^ 1);
        if (lane < KS) {
            const int s = lane;
            const uint32_t qrb = lds_off(&sQR[buf][0][0]) + 4u * s;
            const uint32_t zbb = lds_off(&sZ[buf][0][0]) + 4u * s;
            const uint32_t gbb = lds_off(&sG[buf][0]);
            float* op = ob + (size_t)k * TILE * KS + s;

            Grp4 GA, GB;
            issue_grp(GA, qrb, zbb, gbb, 0);
#pragma unroll 1
            for (int jj = 0; jj < 15; ++jj) {
                issue_grp(GB, qrb, zbb, gbb, 2 * jj + 1);
                LGKM_WAIT(5);
                consume_grp(GA, mu, Pv, op + (size_t)(8 * jj) * KS);
                issue_grp(GA, qrb, zbb, gbb, 2 * jj + 2);
                LGKM_WAIT(5);
                consume_grp(GB, mu, Pv, op + (size_t)(8 * jj + 4) * KS);
            }
            issue_grp(GB, qrb, zbb, gbb, 31);
            LGKM_WAIT(5);
            consume_grp(GA, mu, Pv, op + (size_t)120 * KS);
            LGKM_WAIT(0);
            consume_grp(GB, mu, Pv, op + (size_t)124 * KS);
        }
        // tile k+1 staging (and this tile's out stores) must land before buffer reuse
        asm volatile("s_waitcnt vmcnt(0)" ::: "memory");
        __builtin_amdgcn_sched_barrier(0);
    }
}

// ---------------- fallback: fused kernel (if ws too small) ----------------
#define KTT 128
#define KNT (KT / KTT)
#define SROW (KS + 1)

__global__ __launch_bounds__(320, 2) void kalman_fused(
    const float* __restrict__ z, const float* __restrict__ p,
    const float* __restrict__ mu0, const float* __restrict__ P0,
    const float* __restrict__ Wq1, const float* __restrict__ bq1,
    const float* __restrict__ Wq2, const float* __restrict__ bq2,
    const float* __restrict__ Wr1, const float* __restrict__ br1,
    const float* __restrict__ Wr2, const float* __restrict__ br2,
    const float* __restrict__ Wg1, const float* __restrict__ bg1,
    const float* __restrict__ Wg2, const float* __restrict__ bg2,
    float* __restrict__ out)
{
    __shared__ float sQ[2][KTT][SROW];
    __shared__ float sR[2][KTT][SROW];
    __shared__ float sZf[2][KTT][KS];
    __shared__ float sGf[2][KTT];

    const int b = blockIdx.x;
    const int tid = threadIdx.x;
    const float* __restrict__ zb = z + (size_t)b * KT * KS;
    const float* __restrict__ pb = p + (size_t)b * KT * KPD;
    float* __restrict__ outb = out + (size_t)b * KT * KS;

    const bool is_mlp = (tid < 256);

    auto do_mlp_tile = [&](int tile, int buf) {
        const int tt = tid & (KTT - 1);
        const int t = tile * KTT + tt;
        const float4 pv = *reinterpret_cast<const float4*>(pb + (size_t)t * KPD);
        float acc[KS];
        if (tid < KTT) {
            mlp16(pv, Wq1, bq1, Wq2, bq2, acc);
#pragma unroll
            for (int j = 0; j < KS; ++j)
                sQ[buf][tt][j] = softplus_f(acc[j]) + 1e-8f;
            float ag = bg2[0];
#pragma unroll 8
            for (int k = 0; k < 32; ++k) {
                float hk = bg1[k];
                hk = fmaf(pv.x, Wg1[k],      hk);
                hk = fmaf(pv.y, Wg1[32 + k], hk);
                hk = fmaf(pv.z, Wg1[64 + k], hk);
                hk = fmaf(pv.w, Wg1[96 + k], hk);
                hk = fmaxf(hk, 0.0f);
                ag = fmaf(hk, Wg2[k], ag);
            }
            sGf[buf][tt] = sigmoid_f(ag);
        } else {
            mlp16(pv, Wr1, br1, Wr2, br2, acc);
#pragma unroll
            for (int j = 0; j < KS; ++j)
                sR[buf][tt][j] = softplus_f(acc[j]) + 1e-8f;
        }
        const float4* __restrict__ zt =
            reinterpret_cast<const float4*>(zb + (size_t)tile * KTT * KS);
        float4* __restrict__ zd = reinterpret_cast<float4*>(&sZf[buf][0][0]);
        zd[tid] = zt[tid];
        zd[tid + 256] = zt[tid + 256];
    };

    float mu = 0.0f, Pv = 0.0f;
    if (!is_mlp) {
        const int lane = tid - 256;
        if (lane < KS) {
            mu = mu0[(size_t)b * KS + lane];
            Pv = P0[(size_t)b * KS + lane];
        }
    }

    if (is_mlp) do_mlp_tile(0, 0);
    __syncthreads();

    for (int k = 0; k < KNT; ++k) {
        const int cur = k & 1;
        if (is_mlp) {
            if (k + 1 < KNT) do_mlp_tile(k + 1, cur ^ 1);
        } else {
            const int lane = tid - 256;
            if (lane < KS) {
                const int s = lane;
                for (int tt = 0; tt < KTT; ++tt) {
                    const float Ppred = Pv + sQ[cur][tt][s];
                    float Kk = Ppred * __builtin_amdgcn_rcpf(Ppred + sR[cur][tt][s]);
                    Kk = __builtin_amdgcn_fmed3f(Kk, 1e-6f, 0.95f);
                    mu = fmaf(sGf[cur][tt] * Kk, sZf[cur][tt][s] - mu, mu);
                    Pv = fmaf(-Kk, Ppred, Ppred);
                    outb[(size_t)(k * KTT + tt) * KS + s] = mu;
                }
            }
        }
        __syncthreads();
    }
}

// ---------------- launcher ----------------
extern "C" void kernel_launch(void* const* d_in, const int* in_sizes, int n_in,
                              void* d_out, int out_size, void* d_ws, size_t ws_size,
                              hipStream_t stream) {
    const float* z   = (const float*)d_in[0];
    const float* p   = (const float*)d_in[1];
    const float* mu0 = (const float*)d_in[2];
    const float* P0  = (const float*)d_in[3];
    const float* Wq1 = (const float*)d_in[4];
    const float* bq1 = (const float*)d_in[5];
    const float* Wq2 = (const float*)d_in[6];
    const float* bq2 = (const float*)d_in[7];
    const float* Wr1 = (const float*)d_in[8];
    const float* br1 = (const float*)d_in[9];
    const float* Wr2 = (const float*)d_in[10];
    const float* br2 = (const float*)d_in[11];
    const float* Wg1 = (const float*)d_in[12];
    const float* bg1 = (const float*)d_in[13];
    const float* Wg2 = (const float*)d_in[14];
    const float* bg2 = (const float*)d_in[15];
    float* out = (float*)d_out;

    const size_t QR_BYTES = (size_t)KB * KS * KT * 4;   // 67,108,864
    const size_t G_BYTES  = (size_t)KB * KT * 4;        //  4,194,304

    if (ws_size >= QR_BYTES + G_BYTES) {
        uint32_t* qr_ws = (uint32_t*)d_ws;
        float* g_ws = (float*)((char*)d_ws + QR_BYTES);
        hipLaunchKernelGGL(mlp_kernel, dim3((KB * KT) / 256), dim3(256), 0, stream,
                           p, Wq1, bq1, Wq2, bq2, Wr1, br1, Wr2, br2,
                           Wg1, bg1, Wg2, bg2, qr_ws, g_ws);
        hipLaunchKernelGGL(scan_kernel, dim3(KB), dim3(64), 0, stream,
                           qr_ws, g_ws, z, mu0, P0, out);
    } else {
        hipLaunchKernelGGL(kalman_fused, dim3(KB), dim3(320), 0, stream,
                           z, p, mu0, P0, Wq1, bq1, Wq2, bq2,
                           Wr1, br1, Wr2, br2, Wg1, bg1, Wg2, bg2, out);
    }
}

// Round 7
// 129.554 us; speedup vs baseline: 1.5592x; 1.5592x over previous
//
#include <hip/hip_runtime.h>
#include <hip/hip_fp16.h>
#include <stdint.h>
#include <math.h>

#define KB 512
#define KT 2048
#define KS 16
#define KPD 4
#define QT 512          // timesteps per quarter
#define NQ (KT / QT)    // 4 quarters
#define CL 8            // chunk length (steps per lane)
#define NC (QT / CL)    // 64 chunks = 64 lanes

// ---------------- shared helpers ----------------
__device__ __forceinline__ float softplus_f(float x) {
    float ax = fabsf(x);
    float e  = __expf(-ax);
    return fmaxf(x, 0.0f) + __logf(1.0f + e);
}
__device__ __forceinline__ float sigmoid_f(float x) {
    return __builtin_amdgcn_rcpf(1.0f + __expf(-x));
}
__device__ __forceinline__ float h2f_lo(uint32_t w) {
    return __half2float(__ushort_as_half((unsigned short)(w & 0xffffu)));
}
__device__ __forceinline__ float h2f_hi(uint32_t w) {
    return __half2float(__ushort_as_half((unsigned short)(w >> 16)));
}

__device__ __forceinline__ void mlp16(const float4 pv,
    const float* __restrict__ W1, const float* __restrict__ b1,
    const float* __restrict__ W2, const float* __restrict__ b2,
    float* __restrict__ acc)
{
#pragma unroll
    for (int j = 0; j < KS; ++j) acc[j] = b2[j];
#pragma unroll 4
    for (int k = 0; k < 64; ++k) {
        float hk = b1[k];
        hk = fmaf(pv.x, W1[k],       hk);
        hk = fmaf(pv.y, W1[64 + k],  hk);
        hk = fmaf(pv.z, W1[128 + k], hk);
        hk = fmaf(pv.w, W1[192 + k], hk);
        hk = fmaxf(hk, 0.0f);
#pragma unroll
        for (int j = 0; j < KS; ++j) acc[j] = fmaf(hk, W2[k * KS + j], acc[j]);
    }
}

// ---------------- K1: embarrassingly-parallel MLPs ----------------
// ws layout: qr_ws[b][s][t] (u32 = fp16 Q | fp16 R << 16), g_ws[b][t] (f32)
__global__ __launch_bounds__(256) void mlp_kernel(
    const float* __restrict__ p,
    const float* __restrict__ Wq1, const float* __restrict__ bq1,
    const float* __restrict__ Wq2, const float* __restrict__ bq2,
    const float* __restrict__ Wr1, const float* __restrict__ br1,
    const float* __restrict__ Wr2, const float* __restrict__ br2,
    const float* __restrict__ Wg1, const float* __restrict__ bg1,
    const float* __restrict__ Wg2, const float* __restrict__ bg2,
    uint32_t* __restrict__ qr_ws, float* __restrict__ g_ws)
{
    const int idx = blockIdx.x * 256 + threadIdx.x;   // global (b,t)
    const int b = idx >> 11;
    const int t = idx & (KT - 1);
    const float4 pv = reinterpret_cast<const float4*>(p)[idx];

    float accQ[KS], accR[KS];
    mlp16(pv, Wq1, bq1, Wq2, bq2, accQ);
    mlp16(pv, Wr1, br1, Wr2, br2, accR);

    float ag = bg2[0];
#pragma unroll 4
    for (int k = 0; k < 32; ++k) {
        float hk = bg1[k];
        hk = fmaf(pv.x, Wg1[k],      hk);
        hk = fmaf(pv.y, Wg1[32 + k], hk);
        hk = fmaf(pv.z, Wg1[64 + k], hk);
        hk = fmaf(pv.w, Wg1[96 + k], hk);
        hk = fmaxf(hk, 0.0f);
        ag = fmaf(hk, Wg2[k], ag);
    }
    g_ws[idx] = sigmoid_f(ag);

    uint32_t* qb = qr_ws + (size_t)b * KS * KT + t;
#pragma unroll
    for (int j = 0; j < KS; ++j) {
        float Qv = softplus_f(accQ[j]) + 1e-8f;
        float Rv = softplus_f(accR[j]) + 1e-8f;
        uint32_t lo = (uint32_t)__half_as_ushort(__float2half_rn(Qv));
        uint32_t hi = (uint32_t)__half_as_ushort(__float2half_rn(Rv));
        qb[(size_t)j * KT] = lo | (hi << 16);    // coalesced per j (t fast)
    }
}

// ---------------- K2: parallel-scan Kalman (Mobius + affine) ----------------
// Block = one b. 1024 threads = 16 s-waves x 64 chunk-lanes. Per quarter (512 t):
//  ph1 stage z,gamma -> LDS | ph2 per-lane 8-step Mobius composite |
//  ph3 intra-wave shfl scan -> chunk-start P | ph4 exact 8-step P/K recompute |
//  ph5 affine shfl scan -> chunk-start mu | ph6 mu recompute -> LDS |
//  ph7 coalesced transpose store.
__global__ __launch_bounds__(1024) void scan_kernel(
    const uint32_t* __restrict__ qr_ws, const float* __restrict__ g_ws,
    const float* __restrict__ z, const float* __restrict__ mu0,
    const float* __restrict__ P0, float* __restrict__ out)
{
    __shared__ float smem[QT * 17 + QT];   // z/mu stage [512][17] + gamma [512]
    float* zmu = smem;
    float* gl  = smem + QT * 17;

    const int b = blockIdx.x;
    const int tid = threadIdx.x;
    const int lane = tid & 63;             // chunk index c = 0..63
    const int s = tid >> 6;                // state index 0..15

    const uint32_t* qrow = qr_ws + (size_t)(b * KS + s) * KT;
    const float* zb = z + (size_t)b * KT * KS;
    const float* gb = g_ws + (size_t)b * KT;
    float* ob = out + (size_t)b * KT * KS;

    float P_q  = P0[b * KS + s];
    float mu_q = mu0[b * KS + s];

    for (int q = 0; q < NQ; ++q) {
        const int t0 = q * QT;

        // ---- phase 1: stage z quarter (f32, padded rows) + gamma ----
        {
            const float4* zq = reinterpret_cast<const float4*>(zb + (size_t)t0 * KS);
#pragma unroll
            for (int v = 0; v < 2; ++v) {
                int k = tid * 2 + v;               // float4 id, 2048 total
                float4 w = zq[k];
                int t = k >> 2, s0 = (k & 3) << 2;
                zmu[t * 17 + s0 + 0] = w.x;
                zmu[t * 17 + s0 + 1] = w.y;
                zmu[t * 17 + s0 + 2] = w.z;
                zmu[t * 17 + s0 + 3] = w.w;
            }
            if (tid < QT) gl[tid] = gb[t0 + tid];
        }
        __syncthreads();

        // ---- phase 2: load 8 QR words, build raw Mobius composite ----
        uint32_t qr[CL];
        {
            const uint4* qp = reinterpret_cast<const uint4*>(qrow + t0 + lane * CL);
            uint4 u0 = qp[0], u1 = qp[1];
            qr[0] = u0.x; qr[1] = u0.y; qr[2] = u0.z; qr[3] = u0.w;
            qr[4] = u1.x; qr[5] = u1.y; qr[6] = u1.z; qr[7] = u1.w;
        }
        float c00 = 1.f, c01 = 0.f, c10 = 0.f, c11 = 1.f;
#pragma unroll
        for (int i = 0; i < CL; ++i) {
            float Q = h2f_lo(qr[i]), R = h2f_hi(qr[i]);
            float ta = fmaf(Q, c10, c00);
            float tb = fmaf(Q, c11, c01);
            float n10 = fmaf(Q + R, c10, c00);
            float n11 = fmaf(Q + R, c11, c01);
            c00 = R * ta; c01 = R * tb; c10 = n10; c11 = n11;
        }
        float rn = __builtin_amdgcn_rcpf(c11);
        float ma = c00 * rn, mb = c01 * rn, mc = c10 * rn;   // d == 1

        // ---- phase 3: intra-wave inclusive Mobius scan (Hillis-Steele) ----
#pragma unroll
        for (int r = 0; r < 6; ++r) {
            const int d = 1 << r;
            float pa = __shfl_up(ma, d);
            float pb = __shfl_up(mb, d);
            float pc = __shfl_up(mc, d);
            // self (later) compose older: N = M_self * M_older
            float na = fmaf(ma, pa, mb * pc);
            float nb = fmaf(ma, pb, mb);
            float nc = fmaf(mc, pa, pc);
            float nd = fmaf(mc, pb, 1.f);
            float rr = __builtin_amdgcn_rcpf(nd);
            bool act = (lane >= d);
            ma = act ? na * rr : ma;
            mb = act ? nb * rr : mb;
            mc = act ? nc * rr : mc;
        }
        float ea = __shfl_up(ma, 1);
        float eb = __shfl_up(mb, 1);
        float ec = __shfl_up(mc, 1);
        if (lane == 0) { ea = 1.f; eb = 0.f; ec = 0.f; }
        float P = fmaf(ea, P_q, eb) * __builtin_amdgcn_rcpf(fmaf(ec, P_q, 1.f));

        // ---- phase 4: exact 8-step P/K recompute (with clip) + affine build ----
        float av[CL], bw[CL];
        float A = 1.f, Bv = 0.f;
#pragma unroll
        for (int i = 0; i < CL; ++i) {
            float Q = h2f_lo(qr[i]), R = h2f_hi(qr[i]);
            float Pp = P + Q;
            float K0 = Pp * __builtin_amdgcn_rcpf(Pp + R);
            float Kk = __builtin_amdgcn_fmed3f(K0, 1e-6f, 0.95f);
            int t = lane * CL + i;
            float g = gl[t];
            float gk = g * Kk;
            float zv = zmu[t * 17 + s];
            av[i] = 1.f - gk;
            bw[i] = gk * zv;
            P = fmaf(-Kk, Pp, Pp);
            A = A * av[i];
            Bv = fmaf(av[i], Bv, bw[i]);
        }
        float P_end = __shfl(P, 63);

        // ---- phase 5: intra-wave affine scan ----
#pragma unroll
        for (int r = 0; r < 6; ++r) {
            const int d = 1 << r;
            float pA = __shfl_up(A, d);
            float pB = __shfl_up(Bv, d);
            float nA = A * pA;
            float nB = fmaf(A, pB, Bv);
            bool act = (lane >= d);
            A  = act ? nA : A;
            Bv = act ? nB : Bv;
        }
        float eA = __shfl_up(A, 1);
        float eB = __shfl_up(Bv, 1);
        if (lane == 0) { eA = 1.f; eB = 0.f; }
        float mu = fmaf(eA, mu_q, eB);

        __syncthreads();   // all waves done reading z before mu overwrites it

        // ---- phase 6: mu within-chunk recompute, stage to LDS ----
#pragma unroll
        for (int i = 0; i < CL; ++i) {
            mu = fmaf(av[i], mu, bw[i]);
            zmu[(lane * CL + i) * 17 + s] = mu;
        }
        float mu_end = __shfl(mu, 63);
        __syncthreads();

        // ---- phase 7: coalesced transpose store ----
#pragma unroll
        for (int v = 0; v < 2; ++v) {
            int k = tid * 2 + v;
            int t = k >> 2, s0 = (k & 3) << 2;
            float4 w;
            w.x = zmu[t * 17 + s0 + 0];
            w.y = zmu[t * 17 + s0 + 1];
            w.z = zmu[t * 17 + s0 + 2];
            w.w = zmu[t * 17 + s0 + 3];
            *reinterpret_cast<float4*>(ob + (size_t)(t0 + t) * KS + s0) = w;
        }
        P_q  = P_end;
        mu_q = mu_end;
        __syncthreads();   // before next quarter's phase 1 overwrites LDS
    }
}

// ---------------- fallback: fused kernel (if ws too small) ----------------
#define KTT 128
#define KNT (KT / KTT)
#define SROW (KS + 1)

__global__ __launch_bounds__(320, 2) void kalman_fused(
    const float* __restrict__ z, const float* __restrict__ p,
    const float* __restrict__ mu0, const float* __restrict__ P0,
    const float* __restrict__ Wq1, const float* __restrict__ bq1,
    const float* __restrict__ Wq2, const float* __restrict__ bq2,
    const float* __restrict__ Wr1, const float* __restrict__ br1,
    const float* __restrict__ Wr2, const float* __restrict__ br2,
    const float* __restrict__ Wg1, const float* __restrict__ bg1,
    const float* __restrict__ Wg2, const float* __restrict__ bg2,
    float* __restrict__ out)
{
    __shared__ float sQ[2][KTT][SROW];
    __shared__ float sR[2][KTT][SROW];
    __shared__ float sZf[2][KTT][KS];
    __shared__ float sGf[2][KTT];

    const int b = blockIdx.x;
    const int tid = threadIdx.x;
    const float* __restrict__ zb = z + (size_t)b * KT * KS;
    const float* __restrict__ pb = p + (size_t)b * KT * KPD;
    float* __restrict__ outb = out + (size_t)b * KT * KS;

    const bool is_mlp = (tid < 256);

    auto do_mlp_tile = [&](int tile, int buf) {
        const int tt = tid & (KTT - 1);
        const int t = tile * KTT + tt;
        const float4 pv = *reinterpret_cast<const float4*>(pb + (size_t)t * KPD);
        float acc[KS];
        if (tid < KTT) {
            mlp16(pv, Wq1, bq1, Wq2, bq2, acc);
#pragma unroll
            for (int j = 0; j < KS; ++j)
                sQ[buf][tt][j] = softplus_f(acc[j]) + 1e-8f;
            float ag = bg2[0];
#pragma unroll 8
            for (int k = 0; k < 32; ++k) {
                float hk = bg1[k];
                hk = fmaf(pv.x, Wg1[k],      hk);
                hk = fmaf(pv.y, Wg1[32 + k], hk);
                hk = fmaf(pv.z, Wg1[64 + k], hk);
                hk = fmaf(pv.w, Wg1[96 + k], hk);
                hk = fmaxf(hk, 0.0f);
                ag = fmaf(hk, Wg2[k], ag);
            }
            sGf[buf][tt] = sigmoid_f(ag);
        } else {
            mlp16(pv, Wr1, br1, Wr2, br2, acc);
#pragma unroll
            for (int j = 0; j < KS; ++j)
                sR[buf][tt][j] = softplus_f(acc[j]) + 1e-8f;
        }
        const float4* __restrict__ zt =
            reinterpret_cast<const float4*>(zb + (size_t)tile * KTT * KS);
        float4* __restrict__ zd = reinterpret_cast<float4*>(&sZf[buf][0][0]);
        zd[tid] = zt[tid];
        zd[tid + 256] = zt[tid + 256];
    };

    float mu = 0.0f, Pv = 0.0f;
    if (!is_mlp) {
        const int lane = tid - 256;
        if (lane < KS) {
            mu = mu0[(size_t)b * KS + lane];
            Pv = P0[(size_t)b * KS + lane];
        }
    }

    if (is_mlp) do_mlp_tile(0, 0);
    __syncthreads();

    for (int k = 0; k < KNT; ++k) {
        const int cur = k & 1;
        if (is_mlp) {
            if (k + 1 < KNT) do_mlp_tile(k + 1, cur ^ 1);
        } else {
            const int lane = tid - 256;
            if (lane < KS) {
                const int s = lane;
                for (int tt = 0; tt < KTT; ++tt) {
                    const float Ppred = Pv + sQ[cur][tt][s];
                    float Kk = Ppred * __builtin_amdgcn_rcpf(Ppred + sR[cur][tt][s]);
                    Kk = __builtin_amdgcn_fmed3f(Kk, 1e-6f, 0.95f);
                    mu = fmaf(sGf[cur][tt] * Kk, sZf[cur][tt][s] - mu, mu);
                    Pv = fmaf(-Kk, Ppred, Ppred);
                    outb[(size_t)(k * KTT + tt) * KS + s] = mu;
                }
            }
        }
        __syncthreads();
    }
}

// ---------------- launcher ----------------
extern "C" void kernel_launch(void* const* d_in, const int* in_sizes, int n_in,
                              void* d_out, int out_size, void* d_ws, size_t ws_size,
                              hipStream_t stream) {
    const float* z   = (const float*)d_in[0];
    const float* p   = (const float*)d_in[1];
    const float* mu0 = (const float*)d_in[2];
    const float* P0  = (const float*)d_in[3];
    const float* Wq1 = (const float*)d_in[4];
    const float* bq1 = (const float*)d_in[5];
    const float* Wq2 = (const float*)d_in[6];
    const float* bq2 = (const float*)d_in[7];
    const float* Wr1 = (const float*)d_in[8];
    const float* br1 = (const float*)d_in[9];
    const float* Wr2 = (const float*)d_in[10];
    const float* br2 = (const float*)d_in[11];
    const float* Wg1 = (const float*)d_in[12];
    const float* bg1 = (const float*)d_in[13];
    const float* Wg2 = (const float*)d_in[14];
    const float* bg2 = (const float*)d_in[15];
    float* out = (float*)d_out;

    const size_t QR_BYTES = (size_t)KB * KS * KT * 4;   // 67,108,864
    const size_t G_BYTES  = (size_t)KB * KT * 4;        //  4,194,304

    if (ws_size >= QR_BYTES + G_BYTES) {
        uint32_t* qr_ws = (uint32_t*)d_ws;
        float* g_ws = (float*)((char*)d_ws + QR_BYTES);
        hipLaunchKernelGGL(mlp_kernel, dim3((KB * KT) / 256), dim3(256), 0, stream,
                           p, Wq1, bq1, Wq2, bq2, Wr1, br1, Wr2, br2,
                           Wg1, bg1, Wg2, bg2, qr_ws, g_ws);
        hipLaunchKernelGGL(scan_kernel, dim3(KB), dim3(1024), 0, stream,
                           qr_ws, g_ws, z, mu0, P0, out);
    } else {
        hipLaunchKernelGGL(kalman_fused, dim3(KB), dim3(320), 0, stream,
                           z, p, mu0, P0, Wq1, bq1, Wq2, bq2,
                           Wr1, br1, Wr2, br2, Wg1, bg1, Wg2, bg2, out);
    }
}

// Round 8
// 105.073 us; speedup vs baseline: 1.9225x; 1.2330x over previous
//
#include <hip/hip_runtime.h>
#include <hip/hip_fp16.h>
#include <stdint.h>
#include <math.h>

#define KB 512
#define KT 2048
#define KS 16
#define KPD 4

typedef _Float16 f16;
typedef _Float16 f16x4v __attribute__((ext_vector_type(4)));
typedef _Float16 f16x8 __attribute__((ext_vector_type(8)));
typedef float f32x4 __attribute__((ext_vector_type(4)));

#define MFMA16(A, B, C) __builtin_amdgcn_mfma_f32_16x16x32_f16(A, B, C, 0, 0, 0)

// ---------------- shared helpers ----------------
__device__ __forceinline__ float softplus_f(float x) {
    float ax = fabsf(x);
    float e  = __expf(-ax);
    return fmaxf(x, 0.0f) + __logf(1.0f + e);
}
__device__ __forceinline__ float sigmoid_f(float x) {
    return __builtin_amdgcn_rcpf(1.0f + __expf(-x));
}
__device__ __forceinline__ float h2f_lo(uint32_t w) {
    return __half2float(__ushort_as_half((unsigned short)(w & 0xffffu)));
}
__device__ __forceinline__ float h2f_hi(uint32_t w) {
    return __half2float(__ushort_as_half((unsigned short)(w >> 16)));
}
__device__ __forceinline__ f16x8 zero8() {
    f16x8 v;
#pragma unroll
    for (int i = 0; i < 8; ++i) v[i] = (f16)0;
    return v;
}

// ---------------- K1: MFMA MLPs ----------------
// Block = 1 wave = 64 consecutive (b,t) rows. GEMM1: H=relu(W1cat^T@P^T+b),
// GEMM2: [Q|R|gamma]=W2cat^T@H+b. Outputs: qr_ws[b][s][t] fp16-packed, g_ws[b][t].
#define HRS 168   // H row stride in f16 (336 B = 84 dw: bank rotation 20/row, 2-way max)

__global__ __launch_bounds__(64) void mlp_kernel(
    const float* __restrict__ p,
    const float* __restrict__ Wq1, const float* __restrict__ bq1,
    const float* __restrict__ Wq2, const float* __restrict__ bq2,
    const float* __restrict__ Wr1, const float* __restrict__ br1,
    const float* __restrict__ Wr2, const float* __restrict__ br2,
    const float* __restrict__ Wg1, const float* __restrict__ bg1,
    const float* __restrict__ Wg2, const float* __restrict__ bg2,
    uint32_t* __restrict__ qr_ws, float* __restrict__ g_ws)
{
    __shared__ __align__(16) f16 Hl[64][HRS];   // [bt][hcol], hcol 0-63 hq, 64-127 hr, 128-159 hg
    __shared__ __align__(16) f16 Pl[64][4];

    const int l = threadIdx.x;
    const int g = l >> 4;
    const int c = l & 15;
    const int row0 = blockIdx.x * 64;
    const int b = row0 >> 11;
    const int t0 = row0 & (KT - 1);

    // ---- const A-frags: W1cat^T, 10 M-tiles (A[row=hcol][k=pd], k>=4 zero) ----
    f16x8 fA1[10];
#pragma unroll
    for (int m = 0; m < 10; ++m) {
        const float* W = (m < 4) ? (Wq1 + m * 16)
                       : (m < 8) ? (Wr1 + (m - 4) * 16)
                                 : (Wg1 + (m - 8) * 16);
        const int ld = (m < 8) ? 64 : 32;
        float w0 = W[0 * ld + c], w1 = W[1 * ld + c],
              w2 = W[2 * ld + c], w3 = W[3 * ld + c];
        f16x8 a = zero8();
        if (g == 0) { a[0] = (f16)w0; a[1] = (f16)w1; a[2] = (f16)w2; a[3] = (f16)w3; }
        fA1[m] = a;
    }

    // ---- const A-frags: W2cat^T, 5 nonzero (m,kk) pairs ----
    // 0:(Q,kk0) 1:(Q,kk1) 2:(R,kk2) 3:(R,kk3) 4:(gamma,kk4)
    f16x8 fA2[5];
#pragma unroll
    for (int i = 0; i < 4; ++i) {
        const float* W = (i < 2) ? Wq2 : Wr2;
        const int kb = (i & 1) * 32;
        f16x8 a;
#pragma unroll
        for (int j = 0; j < 8; ++j) a[j] = (f16)W[(kb + g * 8 + j) * 16 + c];
        fA2[i] = a;
    }
    {
        f16x8 a = zero8();
        if (c == 0) {
#pragma unroll
            for (int j = 0; j < 8; ++j) a[j] = (f16)Wg2[g * 8 + j];
        }
        fA2[4] = a;
    }

    const float bQ0 = bq2[g * 4 + 0], bQ1 = bq2[g * 4 + 1],
                bQ2 = bq2[g * 4 + 2], bQ3 = bq2[g * 4 + 3];
    const float bR0 = br2[g * 4 + 0], bR1 = br2[g * 4 + 1],
                bR2 = br2[g * 4 + 2], bR3 = br2[g * 4 + 3];
    const float bG = bg2[0];

    // ---- stage p tile (f16) ----
    {
        const float4 pv = *reinterpret_cast<const float4*>(p + (size_t)(row0 + l) * KPD);
        f16x4v v; v[0] = (f16)pv.x; v[1] = (f16)pv.y; v[2] = (f16)pv.z; v[3] = (f16)pv.w;
        *reinterpret_cast<f16x4v*>(&Pl[l][0]) = v;
    }
    asm volatile("s_waitcnt lgkmcnt(0)" ::: "memory");
    __builtin_amdgcn_sched_barrier(0);

    // ---- GEMM1 B-frags (P: B[k=pd][col=bt], k>=4 zero) ----
    f16x8 fBP[4];
#pragma unroll
    for (int n = 0; n < 4; ++n) {
        f16x8 v = zero8();
        if (g == 0) {
            f16x4v q = *reinterpret_cast<const f16x4v*>(&Pl[n * 16 + c][0]);
            v[0] = q[0]; v[1] = q[1]; v[2] = q[2]; v[3] = q[3];
        }
        fBP[n] = v;
    }

    // ---- GEMM1: 40 MFMA, epilogue relu+pack -> Hl ----
#pragma unroll
    for (int m = 0; m < 10; ++m) {
        const float* bs = (m < 4) ? (bq1 + m * 16)
                        : (m < 8) ? (br1 + (m - 4) * 16)
                                  : (bg1 + (m - 8) * 16);
        const float b0 = bs[g * 4 + 0], b1 = bs[g * 4 + 1],
                    b2 = bs[g * 4 + 2], b3 = bs[g * 4 + 3];
#pragma unroll
        for (int n = 0; n < 4; ++n) {
            f32x4 acc; acc[0] = b0; acc[1] = b1; acc[2] = b2; acc[3] = b3;
            acc = MFMA16(fA1[m], fBP[n], acc);
            auto h01 = __builtin_amdgcn_cvt_pkrtz(fmaxf(acc[0], 0.f), fmaxf(acc[1], 0.f));
            auto h23 = __builtin_amdgcn_cvt_pkrtz(fmaxf(acc[2], 0.f), fmaxf(acc[3], 0.f));
            uint2 w;
            __builtin_memcpy(&w.x, &h01, 4);
            __builtin_memcpy(&w.y, &h23, 4);
            // D row = hcol m*16+g*4+i, col = bt n*16+c
            *reinterpret_cast<uint2*>(&Hl[n * 16 + c][m * 16 + g * 4]) = w;
        }
    }
    asm volatile("s_waitcnt lgkmcnt(0)" ::: "memory");
    __builtin_amdgcn_sched_barrier(0);

    // ---- GEMM2 + epilogue ----
#pragma unroll
    for (int n = 0; n < 4; ++n) {
        const int bt = n * 16 + c;
        f16x8 fb0 = *reinterpret_cast<const f16x8*>(&Hl[bt][0 * 32 + g * 8]);
        f16x8 fb1 = *reinterpret_cast<const f16x8*>(&Hl[bt][1 * 32 + g * 8]);
        f16x8 fb2 = *reinterpret_cast<const f16x8*>(&Hl[bt][2 * 32 + g * 8]);
        f16x8 fb3 = *reinterpret_cast<const f16x8*>(&Hl[bt][3 * 32 + g * 8]);
        f16x8 fb4 = *reinterpret_cast<const f16x8*>(&Hl[bt][4 * 32 + g * 8]);

        f32x4 aq; aq[0] = bQ0; aq[1] = bQ1; aq[2] = bQ2; aq[3] = bQ3;
        aq = MFMA16(fA2[0], fb0, aq);
        aq = MFMA16(fA2[1], fb1, aq);
        f32x4 ar; ar[0] = bR0; ar[1] = bR1; ar[2] = bR2; ar[3] = bR3;
        ar = MFMA16(fA2[2], fb2, ar);
        ar = MFMA16(fA2[3], fb3, ar);
        f32x4 ag; ag[0] = 0.f; ag[1] = 0.f; ag[2] = 0.f; ag[3] = 0.f;
        ag = MFMA16(fA2[4], fb4, ag);

        uint32_t* qdst = qr_ws + ((size_t)b * KS + g * 4) * KT + t0 + bt;
#pragma unroll
        for (int i = 0; i < 4; ++i) {
            float Qv = softplus_f(aq[i]) + 1e-8f;
            float Rv = softplus_f(ar[i]) + 1e-8f;
            auto pk = __builtin_amdgcn_cvt_pkrtz(Qv, Rv);
            uint32_t w; __builtin_memcpy(&w, &pk, 4);
            qdst[(size_t)i * KT] = w;
        }
        if (g == 0)
            g_ws[(size_t)b * KT + t0 + bt] = sigmoid_f(ag[0] + bG);
    }
}

// ---------------- K2: parallel-scan Kalman (Mobius + affine) — unchanged R7 ----------------
#define QT 512
#define NQ (KT / QT)
#define CL 8

__global__ __launch_bounds__(1024) void scan_kernel(
    const uint32_t* __restrict__ qr_ws, const float* __restrict__ g_ws,
    const float* __restrict__ z, const float* __restrict__ mu0,
    const float* __restrict__ P0, float* __restrict__ out)
{
    __shared__ float smem[QT * 17 + QT];
    float* zmu = smem;
    float* gl  = smem + QT * 17;

    const int b = blockIdx.x;
    const int tid = threadIdx.x;
    const int lane = tid & 63;
    const int s = tid >> 6;

    const uint32_t* qrow = qr_ws + (size_t)(b * KS + s) * KT;
    const float* zb = z + (size_t)b * KT * KS;
    const float* gb = g_ws + (size_t)b * KT;
    float* ob = out + (size_t)b * KT * KS;

    float P_q  = P0[b * KS + s];
    float mu_q = mu0[b * KS + s];

    for (int q = 0; q < NQ; ++q) {
        const int t0 = q * QT;

        {
            const float4* zq = reinterpret_cast<const float4*>(zb + (size_t)t0 * KS);
#pragma unroll
            for (int v = 0; v < 2; ++v) {
                int k = tid * 2 + v;
                float4 w = zq[k];
                int t = k >> 2, s0 = (k & 3) << 2;
                zmu[t * 17 + s0 + 0] = w.x;
                zmu[t * 17 + s0 + 1] = w.y;
                zmu[t * 17 + s0 + 2] = w.z;
                zmu[t * 17 + s0 + 3] = w.w;
            }
            if (tid < QT) gl[tid] = gb[t0 + tid];
        }
        __syncthreads();

        uint32_t qr[CL];
        {
            const uint4* qp = reinterpret_cast<const uint4*>(qrow + t0 + lane * CL);
            uint4 u0 = qp[0], u1 = qp[1];
            qr[0] = u0.x; qr[1] = u0.y; qr[2] = u0.z; qr[3] = u0.w;
            qr[4] = u1.x; qr[5] = u1.y; qr[6] = u1.z; qr[7] = u1.w;
        }
        float c00 = 1.f, c01 = 0.f, c10 = 0.f, c11 = 1.f;
#pragma unroll
        for (int i = 0; i < CL; ++i) {
            float Q = h2f_lo(qr[i]), R = h2f_hi(qr[i]);
            float ta = fmaf(Q, c10, c00);
            float tb = fmaf(Q, c11, c01);
            float n10 = fmaf(Q + R, c10, c00);
            float n11 = fmaf(Q + R, c11, c01);
            c00 = R * ta; c01 = R * tb; c10 = n10; c11 = n11;
        }
        float rn = __builtin_amdgcn_rcpf(c11);
        float ma = c00 * rn, mb = c01 * rn, mc = c10 * rn;

#pragma unroll
        for (int r = 0; r < 6; ++r) {
            const int d = 1 << r;
            float pa = __shfl_up(ma, d);
            float pb = __shfl_up(mb, d);
            float pc = __shfl_up(mc, d);
            float na = fmaf(ma, pa, mb * pc);
            float nb = fmaf(ma, pb, mb);
            float nc = fmaf(mc, pa, pc);
            float nd = fmaf(mc, pb, 1.f);
            float rr = __builtin_amdgcn_rcpf(nd);
            bool act = (lane >= d);
            ma = act ? na * rr : ma;
            mb = act ? nb * rr : mb;
            mc = act ? nc * rr : mc;
        }
        float ea = __shfl_up(ma, 1);
        float eb = __shfl_up(mb, 1);
        float ec = __shfl_up(mc, 1);
        if (lane == 0) { ea = 1.f; eb = 0.f; ec = 0.f; }
        float P = fmaf(ea, P_q, eb) * __builtin_amdgcn_rcpf(fmaf(ec, P_q, 1.f));

        float av[CL], bw[CL];
        float A = 1.f, Bv = 0.f;
#pragma unroll
        for (int i = 0; i < CL; ++i) {
            float Q = h2f_lo(qr[i]), R = h2f_hi(qr[i]);
            float Pp = P + Q;
            float K0 = Pp * __builtin_amdgcn_rcpf(Pp + R);
            float Kk = __builtin_amdgcn_fmed3f(K0, 1e-6f, 0.95f);
            int t = lane * CL + i;
            float g = gl[t];
            float gk = g * Kk;
            float zv = zmu[t * 17 + s];
            av[i] = 1.f - gk;
            bw[i] = gk * zv;
            P = fmaf(-Kk, Pp, Pp);
            A = A * av[i];
            Bv = fmaf(av[i], Bv, bw[i]);
        }
        float P_end = __shfl(P, 63);

#pragma unroll
        for (int r = 0; r < 6; ++r) {
            const int d = 1 << r;
            float pA = __shfl_up(A, d);
            float pB = __shfl_up(Bv, d);
            float nA = A * pA;
            float nB = fmaf(A, pB, Bv);
            bool act = (lane >= d);
            A  = act ? nA : A;
            Bv = act ? nB : Bv;
        }
        float eA = __shfl_up(A, 1);
        float eB = __shfl_up(Bv, 1);
        if (lane == 0) { eA = 1.f; eB = 0.f; }
        float mu = fmaf(eA, mu_q, eB);

        __syncthreads();

#pragma unroll
        for (int i = 0; i < CL; ++i) {
            mu = fmaf(av[i], mu, bw[i]);
            zmu[(lane * CL + i) * 17 + s] = mu;
        }
        float mu_end = __shfl(mu, 63);
        __syncthreads();

#pragma unroll
        for (int v = 0; v < 2; ++v) {
            int k = tid * 2 + v;
            int t = k >> 2, s0 = (k & 3) << 2;
            float4 w;
            w.x = zmu[t * 17 + s0 + 0];
            w.y = zmu[t * 17 + s0 + 1];
            w.z = zmu[t * 17 + s0 + 2];
            w.w = zmu[t * 17 + s0 + 3];
            *reinterpret_cast<float4*>(ob + (size_t)(t0 + t) * KS + s0) = w;
        }
        P_q  = P_end;
        mu_q = mu_end;
        __syncthreads();
    }
}

// ---------------- fallback: fused kernel (if ws too small) ----------------
#define KTT 128
#define KNT (KT / KTT)
#define SROW (KS + 1)

__device__ __forceinline__ void mlp16(const float4 pv,
    const float* __restrict__ W1, const float* __restrict__ b1,
    const float* __restrict__ W2, const float* __restrict__ b2,
    float* __restrict__ acc)
{
#pragma unroll
    for (int j = 0; j < KS; ++j) acc[j] = b2[j];
#pragma unroll 4
    for (int k = 0; k < 64; ++k) {
        float hk = b1[k];
        hk = fmaf(pv.x, W1[k],       hk);
        hk = fmaf(pv.y, W1[64 + k],  hk);
        hk = fmaf(pv.z, W1[128 + k], hk);
        hk = fmaf(pv.w, W1[192 + k], hk);
        hk = fmaxf(hk, 0.0f);
#pragma unroll
        for (int j = 0; j < KS; ++j) acc[j] = fmaf(hk, W2[k * KS + j], acc[j]);
    }
}

__global__ __launch_bounds__(320, 2) void kalman_fused(
    const float* __restrict__ z, const float* __restrict__ p,
    const float* __restrict__ mu0, const float* __restrict__ P0,
    const float* __restrict__ Wq1, const float* __restrict__ bq1,
    const float* __restrict__ Wq2, const float* __restrict__ bq2,
    const float* __restrict__ Wr1, const float* __restrict__ br1,
    const float* __restrict__ Wr2, const float* __restrict__ br2,
    const float* __restrict__ Wg1, const float* __restrict__ bg1,
    const float* __restrict__ Wg2, const float* __restrict__ bg2,
    float* __restrict__ out)
{
    __shared__ float sQ[2][KTT][SROW];
    __shared__ float sR[2][KTT][SROW];
    __shared__ float sZf[2][KTT][KS];
    __shared__ float sGf[2][KTT];

    const int b = blockIdx.x;
    const int tid = threadIdx.x;
    const float* __restrict__ zb = z + (size_t)b * KT * KS;
    const float* __restrict__ pb = p + (size_t)b * KT * KPD;
    float* __restrict__ outb = out + (size_t)b * KT * KS;

    const bool is_mlp = (tid < 256);

    auto do_mlp_tile = [&](int tile, int buf) {
        const int tt = tid & (KTT - 1);
        const int t = tile * KTT + tt;
        const float4 pv = *reinterpret_cast<const float4*>(pb + (size_t)t * KPD);
        float acc[KS];
        if (tid < KTT) {
            mlp16(pv, Wq1, bq1, Wq2, bq2, acc);
#pragma unroll
            for (int j = 0; j < KS; ++j)
                sQ[buf][tt][j] = softplus_f(acc[j]) + 1e-8f;
            float ag = bg2[0];
#pragma unroll 8
            for (int k = 0; k < 32; ++k) {
                float hk = bg1[k];
                hk = fmaf(pv.x, Wg1[k],      hk);
                hk = fmaf(pv.y, Wg1[32 + k], hk);
                hk = fmaf(pv.z, Wg1[64 + k], hk);
                hk = fmaf(pv.w, Wg1[96 + k], hk);
                hk = fmaxf(hk, 0.0f);
                ag = fmaf(hk, Wg2[k], ag);
            }
            sGf[buf][tt] = sigmoid_f(ag);
        } else {
            mlp16(pv, Wr1, br1, Wr2, br2, acc);
#pragma unroll
            for (int j = 0; j < KS; ++j)
                sR[buf][tt][j] = softplus_f(acc[j]) + 1e-8f;
        }
        const float4* __restrict__ zt =
            reinterpret_cast<const float4*>(zb + (size_t)tile * KTT * KS);
        float4* __restrict__ zd = reinterpret_cast<float4*>(&sZf[buf][0][0]);
        zd[tid] = zt[tid];
        zd[tid + 256] = zt[tid + 256];
    };

    float mu = 0.0f, Pv = 0.0f;
    if (!is_mlp) {
        const int lane = tid - 256;
        if (lane < KS) {
            mu = mu0[(size_t)b * KS + lane];
            Pv = P0[(size_t)b * KS + lane];
        }
    }

    if (is_mlp) do_mlp_tile(0, 0);
    __syncthreads();

    for (int k = 0; k < KNT; ++k) {
        const int cur = k & 1;
        if (is_mlp) {
            if (k + 1 < KNT) do_mlp_tile(k + 1, cur ^ 1);
        } else {
            const int lane = tid - 256;
            if (lane < KS) {
                const int s = lane;
                for (int tt = 0; tt < KTT; ++tt) {
                    const float Ppred = Pv + sQ[cur][tt][s];
                    float Kk = Ppred * __builtin_amdgcn_rcpf(Ppred + sR[cur][tt][s]);
                    Kk = __builtin_amdgcn_fmed3f(Kk, 1e-6f, 0.95f);
                    mu = fmaf(sGf[cur][tt] * Kk, sZf[cur][tt][s] - mu, mu);
                    Pv = fmaf(-Kk, Ppred, Ppred);
                    outb[(size_t)(k * KTT + tt) * KS + s] = mu;
                }
            }
        }
        __syncthreads();
    }
}

// ---------------- launcher ----------------
extern "C" void kernel_launch(void* const* d_in, const int* in_sizes, int n_in,
                              void* d_out, int out_size, void* d_ws, size_t ws_size,
                              hipStream_t stream) {
    const float* z   = (const float*)d_in[0];
    const float* p   = (const float*)d_in[1];
    const float* mu0 = (const float*)d_in[2];
    const float* P0  = (const float*)d_in[3];
    const float* Wq1 = (const float*)d_in[4];
    const float* bq1 = (const float*)d_in[5];
    const float* Wq2 = (const float*)d_in[6];
    const float* bq2 = (const float*)d_in[7];
    const float* Wr1 = (const float*)d_in[8];
    const float* br1 = (const float*)d_in[9];
    const float* Wr2 = (const float*)d_in[10];
    const float* br2 = (const float*)d_in[11];
    const float* Wg1 = (const float*)d_in[12];
    const float* bg1 = (const float*)d_in[13];
    const float* Wg2 = (const float*)d_in[14];
    const float* bg2 = (const float*)d_in[15];
    float* out = (float*)d_out;

    const size_t QR_BYTES = (size_t)KB * KS * KT * 4;   // 67,108,864
    const size_t G_BYTES  = (size_t)KB * KT * 4;        //  4,194,304

    if (ws_size >= QR_BYTES + G_BYTES) {
        uint32_t* qr_ws = (uint32_t*)d_ws;
        float* g_ws = (float*)((char*)d_ws + QR_BYTES);
        hipLaunchKernelGGL(mlp_kernel, dim3((KB * KT) / 64), dim3(64), 0, stream,
                           p, Wq1, bq1, Wq2, bq2, Wr1, br1, Wr2, br2,
                           Wg1, bg1, Wg2, bg2, qr_ws, g_ws);
        hipLaunchKernelGGL(scan_kernel, dim3(KB), dim3(1024), 0, stream,
                           qr_ws, g_ws, z, mu0, P0, out);
    } else {
        hipLaunchKernelGGL(kalman_fused, dim3(KB), dim3(320), 0, stream,
                           z, p, mu0, P0, Wq1, bq1, Wq2, bq2,
                           Wr1, br1, Wr2, br2, Wg1, bg1, Wg2, bg2, out);
    }
}